// Round 2
// baseline (171.468 us; speedup 1.0000x reference)
//
#include <hip/hip_runtime.h>

// FANS: B=131072 rows x 16 states, MLP 12->64->64->1 with tanh, fp32 in/out.
// R19: occupancy attack. R18 falsified the grid/LDS-cap theory: grid 2x,
// LDS/4, conflicts->0, yet Occupancy 32->35% and dur flat. New theory: the
// cap is the UNIFIED VGPR+AGPR file. Arch VGPR=64 reported, but c1a/c1b/
// c2a/c2b (4 x f32x16 = 64 accum regs) + a1(32) + w2p(16) push unified
// allocation to ~160/wave -> 3 waves/SIMD = the measured ~35%.
// Changes: (1) w2p moved to LDS (layer-3-only, same-address-per-h reads =
// free broadcast; -16 VGPRs); (2) __launch_bounds__(256,5) forces the
// allocator to the 5-wave/SIMD budget (~96-102 unified regs; est. peak live
// ~96-100 after (1)); (3) layer-3 fdot2 chains split into 2 accums each.
// Kept from R18: permlane32_swap H-exchange (no Hd LDS), 32x32x16 MFMA both
// layers, pk-f16 tanh, zpl planes (wave-local, no barrier), CHUNK=4.
// Tripwires: FETCH>>7MB or dur up with Occupancy flat -> spill, revert to
// (256,4); Occupancy flat ~35% w/o spill -> reg-cap theory wrong, go ILP.

#define N_STATES 16
#define CHUNK    4

typedef _Float16 f16x8  __attribute__((ext_vector_type(8)));
typedef float    f32x16 __attribute__((ext_vector_type(16)));
typedef __fp16   h2     __attribute__((ext_vector_type(2)));
typedef unsigned int u32x2 __attribute__((ext_vector_type(2)));

__device__ __forceinline__ h2 pack2(float a, float b) {
    return __builtin_amdgcn_cvt_pkrtz(a, b);
}
__device__ __forceinline__ unsigned int h2_bits(h2 v) {
    union { h2 h; unsigned int u; } x; x.h = v; return x.u;
}
__device__ __forceinline__ h2 bits_h2(unsigned int v) {
    union { unsigned int u; h2 h; } x; x.u = v; return x.h;
}
__device__ __forceinline__ f16x8 u4_to_h8(uint4 v) {
    union { uint4 u; f16x8 h; } x; x.u = v; return x.h;
}

// Packed-f16 tanh: clamp(+-1.25) then odd Chebyshev poly; v_pk_* full-rate.
__device__ __forceinline__ h2 tanh_pk(h2 x) {
    const h2 hi = {(__fp16)1.25f, (__fp16)1.25f};
    const h2 lo = {(__fp16)-1.25f, (__fp16)-1.25f};
    x = __builtin_elementwise_min(__builtin_elementwise_max(x, lo), hi);
    h2 s = x * x;
    const h2 c4 = {(__fp16)0.00598591f, (__fp16)0.00598591f};
    const h2 c3 = {(__fp16)-0.03807894f, (__fp16)-0.03807894f};
    const h2 c2 = {(__fp16)0.12576901f, (__fp16)0.12576901f};
    const h2 c1 = {(__fp16)-0.33203310f, (__fp16)-0.33203310f};
    const h2 c0 = {(__fp16)0.99998110f, (__fp16)0.99998110f};
    h2 p = s * c4 + c3;
    p = s * p + c2;
    p = s * p + c1;
    p = s * p + c0;
    return x * p;
}

__global__ __launch_bounds__(256, 5) void fans_mfma_kernel(
    const float* __restrict__ x_f, const float* __restrict__ x_b,
    const float* __restrict__ u,   const float* __restrict__ W0,
    const float* __restrict__ W1,  const float* __restrict__ W2,
    float* __restrict__ out)
{
    __shared__ __align__(16) uint4 zplA[256];              // 4 KB: z dwords 0..3
    __shared__ __align__(16) uint2 zplB[256];              // 2 KB: u pair
    __shared__ __align__(16) unsigned int w2l[32];         // 128 B: W2 pair-packed

    const int s   = blockIdx.y;
    const int tid = threadIdx.x;
    const int b0  = blockIdx.x * (256 * CHUNK);

    const int lid = tid & 63;
    const int w   = tid >> 6;     // wave id; wave w owns local rows [64w,64w+64)
    const int n   = lid & 31;     // batch row within 32-tile / feat row for A
    const int h   = lid >> 5;     // K-half (k = 8h+j)

    // ---- layer-1 A-frags in regs (2 x f16x8 = 8 regs) ----
    // a0[Mh][j] = W0[s][feat=32Mh+n][k=8h+j], k<12 else 0
    f16x8 a0[2];
    {
        const float* w0s = W0 + s * 768;
        #pragma unroll
        for (int Mh = 0; Mh < 2; ++Mh) {
            const float* base = w0s + (32 * Mh + n) * 12;
            f16x8 v;
            if (h == 0) {
                const float4 v0 = *(const float4*)(base + 0);
                const float4 v1 = *(const float4*)(base + 4);
                v = (f16x8){(_Float16)v0.x, (_Float16)v0.y, (_Float16)v0.z, (_Float16)v0.w,
                            (_Float16)v1.x, (_Float16)v1.y, (_Float16)v1.z, (_Float16)v1.w};
            } else {
                const float4 v0 = *(const float4*)(base + 8);   // k=8..11
                v = (f16x8){(_Float16)v0.x, (_Float16)v0.y, (_Float16)v0.z, (_Float16)v0.w,
                            (_Float16)0.f, (_Float16)0.f, (_Float16)0.f, (_Float16)0.f};
            }
            a0[Mh] = v;
        }
    }
    // ---- layer-2 A-frags in regs (8 x f16x8 = 32 regs) ----
    // a1[Mh][kc][j] = W1[s][feat_out=32Mh+n][k=16kc+8h+j]
    f16x8 a1[2][4];
    {
        const float* w1s = W1 + s * 4096;
        #pragma unroll
        for (int Mh = 0; Mh < 2; ++Mh) {
            #pragma unroll
            for (int kc = 0; kc < 4; ++kc) {
                const float4* p = (const float4*)(w1s + (32 * Mh + n) * 64 + 16 * kc + 8 * h);
                const float4 v0 = p[0], v1 = p[1];
                a1[Mh][kc] = (f16x8){(_Float16)v0.x, (_Float16)v0.y, (_Float16)v0.z, (_Float16)v0.w,
                                     (_Float16)v1.x, (_Float16)v1.y, (_Float16)v1.z, (_Float16)v1.w};
            }
        }
    }
    // ---- W2 pair-packed into LDS: w2l[i] = pack2(W2[s][2i], W2[s][2i+1]) ----
    // Layer-3 reads are same-address per h-group -> LDS broadcast, no conflict.
    if (tid < 32) {
        const float* w2s = W2 + s * 64;
        w2l[tid] = h2_bits(pack2(w2s[2 * tid], w2s[2 * tid + 1]));
    }
    __syncthreads();

    const int wrap = (s > 8) ? (s - 8) : 0;   // IDX[s] = {0..wrap-1}++{s..15}

    #pragma unroll 1
    for (int ch = 0; ch < CHUNK; ++ch) {
        const int rbase = b0 + ch * 256;

        // ---- phase 1: gather z for own row, pack, write planes ----
        {
            const int row = rbase + tid;
            float zs[8];
            #pragma unroll
            for (int j = 0; j < 8; ++j) {
                const int idx = (j < wrap) ? j : (s + j - wrap);  // uniform
                zs[j] = (idx < 8) ? x_f[row * 8 + idx] : x_b[row * 8 + (idx - 8)];
            }
            const float4 uv = *(const float4*)(u + row * 4);
            zplA[tid] = make_uint4(h2_bits(pack2(zs[0], zs[1])), h2_bits(pack2(zs[2], zs[3])),
                                   h2_bits(pack2(zs[4], zs[5])), h2_bits(pack2(zs[6], zs[7])));
            zplB[tid] = make_uint2(h2_bits(pack2(uv.x, uv.y)), h2_bits(pack2(uv.z, uv.w)));
        }
        // No barrier: wave w reads only rows [64w,64w+64) it wrote itself.

        // ---- phase 2: two 32-row tiles ----
        #pragma unroll
        for (int m = 0; m < 2; ++m) {
            const int rowb = 64 * w + 32 * m;

            // z B-frag: B[k=8h+j][n]: h=0 -> z dwords 0..3; h=1 -> u pair + 0
            f16x8 zf;
            if (h == 0) {
                zf = u4_to_h8(zplA[rowb + n]);
            } else {
                const uint2 b = zplB[rowb + n];
                zf = u4_to_h8(make_uint4(b.x, b.y, 0u, 0u));
            }

            // layer 1: 2 MFMAs (M-halves), C1[Mh][r] = feat 32Mh+(r&3)+8(r>>2)+4h, col n
            const f32x16 z16 = {0.f,0.f,0.f,0.f,0.f,0.f,0.f,0.f,
                                0.f,0.f,0.f,0.f,0.f,0.f,0.f,0.f};
            f32x16 c1a = __builtin_amdgcn_mfma_f32_32x32x16_f16(a0[0], zf, z16, 0, 0, 0);
            f32x16 c1b = __builtin_amdgcn_mfma_f32_32x32x16_f16(a0[1], zf, z16, 0, 0, 0);

            // tanh -> pair-pack, all in regs. pw[2a+e] (c1a) / pw[8+2a+e] (c1b)
            // holds feats (8a+4h+2e, +1) of batch row n.
            unsigned int pw[16];
            #pragma unroll
            for (int a = 0; a < 4; ++a) {
                const int r = 4 * a;
                pw[2 * a + 0]     = h2_bits(tanh_pk(pack2(c1a[r],     c1a[r + 1])));
                pw[2 * a + 1]     = h2_bits(tanh_pk(pack2(c1a[r + 2], c1a[r + 3])));
                pw[8 + 2 * a + 0] = h2_bits(tanh_pk(pack2(c1b[r],     c1b[r + 1])));
                pw[8 + 2 * a + 1] = h2_bits(tanh_pk(pack2(c1b[r + 2], c1b[r + 3])));
            }

            // layer 2: B-frag(kc,h) = feats 16kc+8h+[0..8) of row n, assembled
            // by half-swaps: swap(A,B) -> ({A.lo,B.lo},{A.hi,B.hi}).
            f32x16 c2a = z16, c2b = z16;
            #pragma unroll
            for (int kc = 0; kc < 4; ++kc) {
                const int q = 8 * (kc >> 1) + 4 * (kc & 1);
                u32x2 r0 = __builtin_amdgcn_permlane32_swap(pw[q + 0], pw[q + 2], false, false);
                u32x2 r1 = __builtin_amdgcn_permlane32_swap(pw[q + 1], pw[q + 3], false, false);
                const f16x8 hb = u4_to_h8(make_uint4(r0.x, r1.x, r0.y, r1.y));
                c2a = __builtin_amdgcn_mfma_f32_32x32x16_f16(a1[0][kc], hb, c2a, 0, 0, 0);
                c2b = __builtin_amdgcn_mfma_f32_32x32x16_f16(a1[1][kc], hb, c2b, 0, 0, 0);
            }

            // layer 3: packed tanh + v_dot2; W2 pairs broadcast-read from LDS.
            // Split accumulators: 2-deep chains instead of 4-deep.
            float p0 = 0.f, p1 = 0.f, q0 = 0.f, q1 = 0.f;
            #pragma unroll
            for (int a = 0; a < 4; ++a) {
                const int r = 4 * a;
                const uint2 wa = *(const uint2*)&w2l[4 * a + 2 * h];        // Mh=0
                const uint2 wb = *(const uint2*)&w2l[16 + 4 * a + 2 * h];   // Mh=1
                if (a & 1) {
                    p1 = __builtin_amdgcn_fdot2(tanh_pk(pack2(c2a[r], c2a[r + 1])), bits_h2(wa.x), p1, false);
                    p1 = __builtin_amdgcn_fdot2(tanh_pk(pack2(c2a[r + 2], c2a[r + 3])), bits_h2(wa.y), p1, false);
                    q1 = __builtin_amdgcn_fdot2(tanh_pk(pack2(c2b[r], c2b[r + 1])), bits_h2(wb.x), q1, false);
                    q1 = __builtin_amdgcn_fdot2(tanh_pk(pack2(c2b[r + 2], c2b[r + 3])), bits_h2(wb.y), q1, false);
                } else {
                    p0 = __builtin_amdgcn_fdot2(tanh_pk(pack2(c2a[r], c2a[r + 1])), bits_h2(wa.x), p0, false);
                    p0 = __builtin_amdgcn_fdot2(tanh_pk(pack2(c2a[r + 2], c2a[r + 3])), bits_h2(wa.y), p0, false);
                    q0 = __builtin_amdgcn_fdot2(tanh_pk(pack2(c2b[r], c2b[r + 1])), bits_h2(wb.x), q0, false);
                    q0 = __builtin_amdgcn_fdot2(tanh_pk(pack2(c2b[r + 2], c2b[r + 3])), bits_h2(wb.y), q0, false);
                }
            }
            float acc = (p0 + p1) + (q0 + q1);
            acc += __shfl_xor(acc, 32);       // combine h=0/h=1 halves

            if (lid < 32)
                out[(rbase + rowb + n) * N_STATES + s] = acc;
        }
    }
}

extern "C" void kernel_launch(void* const* d_in, const int* in_sizes, int n_in,
                              void* d_out, int out_size, void* d_ws, size_t ws_size,
                              hipStream_t stream) {
    const float* x_f = (const float*)d_in[0];
    const float* x_b = (const float*)d_in[1];
    const float* u   = (const float*)d_in[2];
    const float* W0  = (const float*)d_in[3];
    const float* W1  = (const float*)d_in[4];
    const float* W2  = (const float*)d_in[5];
    float* out = (float*)d_out;

    const int nb = in_sizes[0] / 8;                 // 131072 = 128 * 1024
    dim3 grid(nb / (256 * CHUNK), N_STATES);        // (128, 16) = 2048 blocks
    fans_mfma_kernel<<<grid, 256, 0, stream>>>(x_f, x_b, u, W0, W1, W2, out);
}

// Round 3
// 121.230 us; speedup vs baseline: 1.4144x; 1.4144x over previous
//
#include <hip/hip_runtime.h>

// FANS: B=131072 rows x 16 states, MLP 12->64->64->1 with tanh, fp32 in/out.
// R20: make 5 waves/SIMD FEASIBLE. R19 proved the unified reg file is the
// occupancy cap: forcing (256,5) at ~128 unified regs spilled (FETCH 41MB).
// Fix: move ALL weights to LDS in MFMA-frag-ready f16 layout, staged once
// per block: sA0 2KB, sA1 8KB, w2l 128B. Per tile: 2+8 ds_read_b128
// (lane-consecutive 16B = conflict-free) + 8 w2 dword broadcasts. This cuts
// ~40 persistent arch VGPRs; c1/c2 accum lifetimes are disjoint (32 shared
// AGPRs) -> peak unified ~95-100 <= 102 -> (256,5) fits WITHOUT spill.
// Opaque-zero offset (asm "+v") per tile defeats LICM re-hoisting the
// loop-invariant weight reads back into persistent regs.
// Kept from R18/19: permlane32_swap H-exchange, 32x32x16 MFMA both layers,
// pk-f16 tanh, zpl planes (wave-local, no barrier), CHUNK=4, split fdot2.
// Tripwires: FETCH>>10MB -> still spilling, revert to (256,4);
// Occupancy up but VALUBusy flat -> latency theory wrong, go ILP.

#define N_STATES 16
#define CHUNK    4

typedef _Float16 f16x8  __attribute__((ext_vector_type(8)));
typedef float    f32x16 __attribute__((ext_vector_type(16)));
typedef __fp16   h2     __attribute__((ext_vector_type(2)));
typedef unsigned int u32x2 __attribute__((ext_vector_type(2)));

__device__ __forceinline__ h2 pack2(float a, float b) {
    return __builtin_amdgcn_cvt_pkrtz(a, b);
}
__device__ __forceinline__ unsigned int h2_bits(h2 v) {
    union { h2 h; unsigned int u; } x; x.h = v; return x.u;
}
__device__ __forceinline__ h2 bits_h2(unsigned int v) {
    union { unsigned int u; h2 h; } x; x.u = v; return x.h;
}
__device__ __forceinline__ f16x8 u4_to_h8(uint4 v) {
    union { uint4 u; f16x8 h; } x; x.u = v; return x.h;
}
__device__ __forceinline__ uint4 pk8(float4 a, float4 b) {
    return make_uint4(h2_bits(pack2(a.x, a.y)), h2_bits(pack2(a.z, a.w)),
                      h2_bits(pack2(b.x, b.y)), h2_bits(pack2(b.z, b.w)));
}

// Packed-f16 tanh: clamp(+-1.25) then odd Chebyshev poly; v_pk_* full-rate.
__device__ __forceinline__ h2 tanh_pk(h2 x) {
    const h2 hi = {(__fp16)1.25f, (__fp16)1.25f};
    const h2 lo = {(__fp16)-1.25f, (__fp16)-1.25f};
    x = __builtin_elementwise_min(__builtin_elementwise_max(x, lo), hi);
    h2 s = x * x;
    const h2 c4 = {(__fp16)0.00598591f, (__fp16)0.00598591f};
    const h2 c3 = {(__fp16)-0.03807894f, (__fp16)-0.03807894f};
    const h2 c2 = {(__fp16)0.12576901f, (__fp16)0.12576901f};
    const h2 c1 = {(__fp16)-0.33203310f, (__fp16)-0.33203310f};
    const h2 c0 = {(__fp16)0.99998110f, (__fp16)0.99998110f};
    h2 p = s * c4 + c3;
    p = s * p + c2;
    p = s * p + c1;
    p = s * p + c0;
    return x * p;
}

__global__ __launch_bounds__(256, 5) void fans_mfma_kernel(
    const float* __restrict__ x_f, const float* __restrict__ x_b,
    const float* __restrict__ u,   const float* __restrict__ W0,
    const float* __restrict__ W1,  const float* __restrict__ W2,
    float* __restrict__ out)
{
    __shared__ __align__(16) uint4 zplA[256];              // 4 KB: z dwords 0..3
    __shared__ __align__(16) uint2 zplB[256];              // 2 KB: u pair
    __shared__ __align__(16) uint4 sA1[8][64];             // 8 KB: W1 frags [Mh*4+kc][h*32+n]
    __shared__ __align__(16) uint4 sA0[2][64];             // 2 KB: W0 frags [Mh][h*32+n]
    __shared__ __align__(16) unsigned int w2l[32];         // 128 B: W2 pair-packed

    const int s   = blockIdx.y;
    const int tid = threadIdx.x;
    const int b0  = blockIdx.x * (256 * CHUNK);

    const int lid = tid & 63;
    const int w   = tid >> 6;     // wave id; wave w owns local rows [64w,64w+64)
    const int n   = lid & 31;     // batch row within 32-tile / feat row for A
    const int h   = lid >> 5;     // K-half (k = 8h+j)

    // ---- stage weights to LDS in frag layout (once per block) ----
    // sA1[Mh*4+kc][h*32+n] = W1[s][32Mh+n][16kc+8h+0..7] as 8 x f16
    {
        const int r  = tid >> 2;          // 0..63 feature row
        const int kc = tid & 3;           // 0..3 K-chunk
        const float* p = W1 + s * 4096 + r * 64 + kc * 16;
        const float4 v0 = ((const float4*)p)[0];
        const float4 v1 = ((const float4*)p)[1];
        const float4 v2 = ((const float4*)p)[2];
        const float4 v3 = ((const float4*)p)[3];
        sA1[(r >> 5) * 4 + kc][(r & 31)]      = pk8(v0, v1);  // h=0: cols +0..7
        sA1[(r >> 5) * 4 + kc][32 + (r & 31)] = pk8(v2, v3);  // h=1: cols +8..15
    }
    // sA0[Mh][h*32+n] = W0[s][32Mh+n][8h+0..7] (h=1: cols 8..11 + zero pad)
    if (tid < 128) {
        const int r  = tid >> 1;          // 0..63 feature row
        const int hh = tid & 1;
        const float* base = W0 + s * 768 + r * 12;
        uint4 v;
        if (hh == 0) {
            const float4 v0 = *(const float4*)(base + 0);
            const float4 v1 = *(const float4*)(base + 4);
            v = pk8(v0, v1);
        } else {
            const float4 v0 = *(const float4*)(base + 8);   // k=8..11
            v = make_uint4(h2_bits(pack2(v0.x, v0.y)), h2_bits(pack2(v0.z, v0.w)), 0u, 0u);
        }
        sA0[r >> 5][hh * 32 + (r & 31)] = v;
    }
    // w2l[i] = pack2(W2[s][2i], W2[s][2i+1]); layer-3 reads broadcast per h.
    if (tid < 32) {
        const float* w2s = W2 + s * 64;
        w2l[tid] = h2_bits(pack2(w2s[2 * tid], w2s[2 * tid + 1]));
    }
    __syncthreads();

    const int wrap = (s > 8) ? (s - 8) : 0;   // IDX[s] = {0..wrap-1}++{s..15}

    #pragma unroll 1
    for (int ch = 0; ch < CHUNK; ++ch) {
        const int rbase = b0 + ch * 256;

        // ---- phase 1: gather z for own row, pack, write planes ----
        {
            const int row = rbase + tid;
            float zs[8];
            #pragma unroll
            for (int j = 0; j < 8; ++j) {
                const int idx = (j < wrap) ? j : (s + j - wrap);  // uniform
                zs[j] = (idx < 8) ? x_f[row * 8 + idx] : x_b[row * 8 + (idx - 8)];
            }
            const float4 uv = *(const float4*)(u + row * 4);
            zplA[tid] = make_uint4(h2_bits(pack2(zs[0], zs[1])), h2_bits(pack2(zs[2], zs[3])),
                                   h2_bits(pack2(zs[4], zs[5])), h2_bits(pack2(zs[6], zs[7])));
            zplB[tid] = make_uint2(h2_bits(pack2(uv.x, uv.y)), h2_bits(pack2(uv.z, uv.w)));
        }
        // No barrier: wave w reads only rows [64w,64w+64) it wrote itself;
        // weight LDS is read-only after the initial sync.

        // ---- phase 2: two 32-row tiles ----
        #pragma unroll
        for (int m = 0; m < 2; ++m) {
            const int rowb = 64 * w + 32 * m;

            // Opaque zero: defeats LICM/CSE so weight ds_reads stay per-tile
            // (normal HIP loads -> compiler manages lgkmcnt; just un-hoistable).
            unsigned int zero = 0;
            asm("" : "+v"(zero));
            const int lz = lid + (int)zero;

            // z B-frag: B[k=8h+j][n]: h=0 -> z dwords 0..3; h=1 -> u pair + 0
            f16x8 zf;
            if (h == 0) {
                zf = u4_to_h8(zplA[rowb + n]);
            } else {
                const uint2 b = zplB[rowb + n];
                zf = u4_to_h8(make_uint4(b.x, b.y, 0u, 0u));
            }

            // layer 1: 2 MFMAs (M-halves), C1[Mh][r] = feat 32Mh+(r&3)+8(r>>2)+4h, col n
            const f32x16 z16 = {0.f,0.f,0.f,0.f,0.f,0.f,0.f,0.f,
                                0.f,0.f,0.f,0.f,0.f,0.f,0.f,0.f};
            const f16x8 a0a = u4_to_h8(sA0[0][lz]);
            const f16x8 a0b = u4_to_h8(sA0[1][lz]);
            f32x16 c1a = __builtin_amdgcn_mfma_f32_32x32x16_f16(a0a, zf, z16, 0, 0, 0);
            f32x16 c1b = __builtin_amdgcn_mfma_f32_32x32x16_f16(a0b, zf, z16, 0, 0, 0);

            // tanh -> pair-pack, all in regs. pw[2a+e] (c1a) / pw[8+2a+e] (c1b)
            // holds feats (8a+4h+2e, +1) of batch row n.
            unsigned int pw[16];
            #pragma unroll
            for (int a = 0; a < 4; ++a) {
                const int r = 4 * a;
                pw[2 * a + 0]     = h2_bits(tanh_pk(pack2(c1a[r],     c1a[r + 1])));
                pw[2 * a + 1]     = h2_bits(tanh_pk(pack2(c1a[r + 2], c1a[r + 3])));
                pw[8 + 2 * a + 0] = h2_bits(tanh_pk(pack2(c1b[r],     c1b[r + 1])));
                pw[8 + 2 * a + 1] = h2_bits(tanh_pk(pack2(c1b[r + 2], c1b[r + 3])));
            }

            // layer 2: B-frag(kc,h) = feats 16kc+8h+[0..8) of row n, assembled
            // by half-swaps: swap(A,B) -> ({A.lo,B.lo},{A.hi,B.hi}).
            // A-frags streamed from LDS per kc.
            f32x16 c2a = z16, c2b = z16;
            #pragma unroll
            for (int kc = 0; kc < 4; ++kc) {
                const int q = 8 * (kc >> 1) + 4 * (kc & 1);
                u32x2 r0 = __builtin_amdgcn_permlane32_swap(pw[q + 0], pw[q + 2], false, false);
                u32x2 r1 = __builtin_amdgcn_permlane32_swap(pw[q + 1], pw[q + 3], false, false);
                const f16x8 hb  = u4_to_h8(make_uint4(r0.x, r1.x, r0.y, r1.y));
                const f16x8 w1a = u4_to_h8(sA1[kc][lz]);
                const f16x8 w1b = u4_to_h8(sA1[4 + kc][lz]);
                c2a = __builtin_amdgcn_mfma_f32_32x32x16_f16(w1a, hb, c2a, 0, 0, 0);
                c2b = __builtin_amdgcn_mfma_f32_32x32x16_f16(w1b, hb, c2b, 0, 0, 0);
            }

            // layer 3: packed tanh + v_dot2; W2 pairs broadcast-read from LDS.
            // Split accumulators: 2-deep chains instead of 4-deep.
            const unsigned int* w2z = &w2l[zero];
            float p0 = 0.f, p1 = 0.f, q0 = 0.f, q1 = 0.f;
            #pragma unroll
            for (int a = 0; a < 4; ++a) {
                const int r = 4 * a;
                const uint2 wa = *(const uint2*)&w2z[4 * a + 2 * h];        // Mh=0
                const uint2 wb = *(const uint2*)&w2z[16 + 4 * a + 2 * h];   // Mh=1
                if (a & 1) {
                    p1 = __builtin_amdgcn_fdot2(tanh_pk(pack2(c2a[r], c2a[r + 1])), bits_h2(wa.x), p1, false);
                    p1 = __builtin_amdgcn_fdot2(tanh_pk(pack2(c2a[r + 2], c2a[r + 3])), bits_h2(wa.y), p1, false);
                    q1 = __builtin_amdgcn_fdot2(tanh_pk(pack2(c2b[r], c2b[r + 1])), bits_h2(wb.x), q1, false);
                    q1 = __builtin_amdgcn_fdot2(tanh_pk(pack2(c2b[r + 2], c2b[r + 3])), bits_h2(wb.y), q1, false);
                } else {
                    p0 = __builtin_amdgcn_fdot2(tanh_pk(pack2(c2a[r], c2a[r + 1])), bits_h2(wa.x), p0, false);
                    p0 = __builtin_amdgcn_fdot2(tanh_pk(pack2(c2a[r + 2], c2a[r + 3])), bits_h2(wa.y), p0, false);
                    q0 = __builtin_amdgcn_fdot2(tanh_pk(pack2(c2b[r], c2b[r + 1])), bits_h2(wb.x), q0, false);
                    q0 = __builtin_amdgcn_fdot2(tanh_pk(pack2(c2b[r + 2], c2b[r + 3])), bits_h2(wb.y), q0, false);
                }
            }
            float acc = (p0 + p1) + (q0 + q1);
            acc += __shfl_xor(acc, 32);       // combine h=0/h=1 halves

            if (lid < 32)
                out[(rbase + rowb + n) * N_STATES + s] = acc;
        }
    }
}

extern "C" void kernel_launch(void* const* d_in, const int* in_sizes, int n_in,
                              void* d_out, int out_size, void* d_ws, size_t ws_size,
                              hipStream_t stream) {
    const float* x_f = (const float*)d_in[0];
    const float* x_b = (const float*)d_in[1];
    const float* u   = (const float*)d_in[2];
    const float* W0  = (const float*)d_in[3];
    const float* W1  = (const float*)d_in[4];
    const float* W2  = (const float*)d_in[5];
    float* out = (float*)d_out;

    const int nb = in_sizes[0] / 8;                 // 131072 = 128 * 1024
    dim3 grid(nb / (256 * CHUNK), N_STATES);        // (128, 16) = 2048 blocks
    fans_mfma_kernel<<<grid, 256, 0, stream>>>(x_f, x_b, u, W0, W1, W2, out);
}